// Round 4
// baseline (639.784 us; speedup 1.0000x reference)
//
#include <hip/hip_runtime.h>
#include <hip/hip_bf16.h>

#define DFEAT 256

typedef __attribute__((ext_vector_type(8))) short bf16x8;
typedef __attribute__((ext_vector_type(4))) float f32x4;

__device__ __forceinline__ float bf2f(unsigned short u) {
  return __builtin_bit_cast(float, ((unsigned)u) << 16);
}
__device__ __forceinline__ unsigned short f2bf(float f) {
  __hip_bfloat16 h = __float2bfloat16(f);  // RTNE
  return *reinterpret_cast<unsigned short*>(&h);
}
__device__ __forceinline__ void gload_lds16(const void* g, void* l) {
  __builtin_amdgcn_global_load_lds(
      (const __attribute__((address_space(1))) void*)g,
      (__attribute__((address_space(3))) void*)l, 16, 0, 0);
}

// ---------------- CSR construction ----------------

__global__ void k_count(const int* __restrict__ ei0, int E, int* __restrict__ cnt) {
  int i = blockIdx.x * blockDim.x + threadIdx.x;
  if (i < E) atomicAdd(&cnt[ei0[i]], 1);
}

// phase 1: per-block inclusive scan of cnt; also dis = rsqrt(deg+1)
__global__ __launch_bounds__(256) void k_scan1(const int* __restrict__ cnt, int N,
                                               int* __restrict__ incl,
                                               int* __restrict__ bsum,
                                               float* __restrict__ dis) {
  __shared__ int sh[256];
  int t = threadIdx.x;
  int i = blockIdx.x * 256 + t;
  int v = (i < N) ? cnt[i] : 0;
  sh[t] = v;
  __syncthreads();
  for (int o = 1; o < 256; o <<= 1) {
    int u = (t >= o) ? sh[t - o] : 0;
    __syncthreads();
    sh[t] += u;
    __syncthreads();
  }
  if (i < N) {
    incl[i] = sh[t];
    dis[i] = rsqrtf((float)(v + 1));
  }
  if (t == 255) bsum[blockIdx.x] = sh[255];
}

// phase 2: exclusive scan of block sums (nb <= 256)
__global__ __launch_bounds__(256) void k_scan2(const int* __restrict__ bsum, int nb,
                                               int* __restrict__ boff) {
  __shared__ int sh[256];
  int t = threadIdx.x;
  int v = (t < nb) ? bsum[t] : 0;
  sh[t] = v;
  __syncthreads();
  for (int o = 1; o < 256; o <<= 1) {
    int u = (t >= o) ? sh[t - o] : 0;
    __syncthreads();
    sh[t] += u;
    __syncthreads();
  }
  if (t < nb) boff[t] = sh[t] - v;  // exclusive
}

// phase 3: rowptr[i] = boff[b] + incl[i] - cnt[i]
__global__ __launch_bounds__(256) void k_scan3(const int* __restrict__ cnt,
                                               const int* __restrict__ incl,
                                               const int* __restrict__ boff, int N, int E,
                                               int* __restrict__ rowptr) {
  int i = blockIdx.x * 256 + threadIdx.x;
  if (i < N) rowptr[i] = boff[blockIdx.x] + incl[i] - cnt[i];
  if (i == 0) rowptr[N] = E;
}

__global__ void k_scatter(const int* __restrict__ ei0, const int* __restrict__ ei1, int E,
                          const int* __restrict__ rowptr, int* __restrict__ cursor,
                          int* __restrict__ cols) {
  int i = blockIdx.x * blockDim.x + threadIdx.x;
  if (i >= E) return;
  int r = ei0[i];
  int pos = rowptr[r] + atomicAdd(&cursor[r], 1);
  cols[pos] = ei1[i];
}

// ---------------- converts ----------------

__global__ void k_f2bf(const float* __restrict__ src, unsigned short* __restrict__ dst,
                       int n4) {
  int i = blockIdx.x * blockDim.x + threadIdx.x;
  if (i >= n4) return;
  float4 f = *(const float4*)(src + (size_t)i * 4);
  ushort4 u;
  u.x = f2bf(f.x); u.y = f2bf(f.y); u.z = f2bf(f.z); u.w = f2bf(f.w);
  *(ushort4*)(dst + (size_t)i * 4) = u;
}

// W[4][256][256] (g,k,n) -> WT[4][256][256] (g,n,k) bf16
__global__ void k_wt(const float* __restrict__ W, unsigned short* __restrict__ WT) {
  int idx = blockIdx.x * 256 + threadIdx.x;
  int n = idx & 255;
  int k = (idx >> 8) & 255;
  int g = idx >> 16;
  WT[(g << 16) | (n << 8) | k] = f2bf(W[idx]);
}

// ---------------- SpMM (bf16, feature-chunked): y = alpha * (L v) + beta * w --
// 8 chunks of 32 feats (3.2 MB < 4 MB L2/XCD); chunk = blockIdx & 7 -> XCD id.
// Block: 4 waves x 4 rows each; wave = 4 edge slots x 16 lanes; lane = 2 feats.
// Laplacian value computed on the fly from dis (L2-resident, 200 KB).

__global__ __launch_bounds__(256) void k_spmm_ch(
    const unsigned short* __restrict__ v, const unsigned short* __restrict__ w,
    unsigned short* __restrict__ y,
    const int* __restrict__ rowptr, const int* __restrict__ cols,
    const float* __restrict__ dis, float alpha, float beta, int N) {
  int ch = blockIdx.x & 7;
  int rbase = (blockIdx.x >> 3) * 16 + (threadIdx.x >> 6) * 4;
  int lane = threadIdx.x & 63;
  int slot = lane >> 4;
  int fo = ch * 32 + (lane & 15) * 2;

  for (int i = 0; i < 4; ++i) {
    int r = rbase + i;
    if (r >= N) return;
    int e0 = rowptr[r], e1 = rowptr[r + 1];
    float dr = dis[r];
    float a0 = 0.f, a1 = 0.f;
    int e = e0 + slot;
    for (; e + 4 < e1; e += 8) {
      int cA = cols[e], cB = cols[e + 4];
      float lA = -dr * dis[cA] + (cA == r ? 1.f : 0.f);
      float lB = -dr * dis[cB] + (cB == r ? 1.f : 0.f);
      unsigned uA = *(const unsigned*)(v + (size_t)cA * DFEAT + fo);
      unsigned uB = *(const unsigned*)(v + (size_t)cB * DFEAT + fo);
      a0 += lA * bf2f(uA & 0xffff) + lB * bf2f(uB & 0xffff);
      a1 += lA * bf2f(uA >> 16) + lB * bf2f(uB >> 16);
    }
    if (e < e1) {
      int c = cols[e];
      float lv = -dr * dis[c] + (c == r ? 1.f : 0.f);
      unsigned u = *(const unsigned*)(v + (size_t)c * DFEAT + fo);
      a0 += lv * bf2f(u & 0xffff);
      a1 += lv * bf2f(u >> 16);
    }
    a0 += __shfl_xor(a0, 16);
    a0 += __shfl_xor(a0, 32);
    a1 += __shfl_xor(a1, 16);
    a1 += __shfl_xor(a1, 32);
    if (slot == 0) {
      float sc = 1.0f - dr * dr;  // appended self-loop value
      unsigned uv = *(const unsigned*)(v + (size_t)r * DFEAT + fo);
      float r0 = alpha * (a0 + sc * bf2f(uv & 0xffff));
      float r1 = alpha * (a1 + sc * bf2f(uv >> 16));
      if (beta != 0.0f) {
        unsigned uw = *(const unsigned*)(w + (size_t)r * DFEAT + fo);
        r0 += beta * bf2f(uw & 0xffff);
        r1 += beta * bf2f(uw >> 16);
      }
      *(unsigned*)(y + (size_t)r * DFEAT + fo) =
          (unsigned)f2bf(r0) | ((unsigned)f2bf(r1) << 16);
    }
  }
}

// ---------------- fused MFMA GEMM: out = sum_g Ag @ Wg + bias ----------------

__global__ __launch_bounds__(256) void k_gemm4(
    const unsigned short* __restrict__ A0, const unsigned short* __restrict__ A1,
    const unsigned short* __restrict__ A2, const unsigned short* __restrict__ A3,
    const unsigned short* __restrict__ WT,  // [4][256][256] (g,n,k)
    const float* __restrict__ bias, float* __restrict__ C, int N) {
  __shared__ __align__(16) unsigned short As[128 * 64];
  __shared__ __align__(16) unsigned short Bs[128 * 64];
  int tid = threadIdx.x;
  int lane = tid & 63;
  int w = tid >> 6;
  int wm = w >> 1, wn = w & 1;
  int brow = blockIdx.x * 128;
  int bcol = blockIdx.y * 128;

  f32x4 acc[4][4] = {};

  int srow = w * 32 + (lane >> 3);
  int skb = ((lane & 7) ^ (lane >> 3)) << 4;

  for (int it = 0; it < 16; ++it) {
    int g = it >> 2;
    int k0 = (it & 3) * 64;
    const unsigned short* Asrc = g == 0 ? A0 : g == 1 ? A1 : g == 2 ? A2 : A3;
    const unsigned short* Bsrc = WT + (g << 16);
    __syncthreads();
#pragma unroll
    for (int c = 0; c < 4; ++c) {
      int r = srow + c * 8;
      int grow = brow + r;
      if (grow >= N) grow = N - 1;
      gload_lds16(Asrc + (size_t)grow * DFEAT + k0 + (skb >> 1),
                  (char*)As + (w * 32 + c * 8) * 128);
      gload_lds16(Bsrc + (size_t)(bcol + r) * DFEAT + k0 + (skb >> 1),
                  (char*)Bs + (w * 32 + c * 8) * 128);
    }
    __syncthreads();
#pragma unroll
    for (int ks = 0; ks < 2; ++ks) {
      bf16x8 af[4], bfr[4];
#pragma unroll
      for (int i = 0; i < 4; ++i) {
        int row = wm * 64 + i * 16 + (lane & 15);
        int kb = (ks * 64 + ((lane >> 4) << 4)) ^ ((row & 7) << 4);
        af[i] = *(const bf16x8*)((const char*)As + row * 128 + kb);
      }
#pragma unroll
      for (int j = 0; j < 4; ++j) {
        int row = wn * 64 + j * 16 + (lane & 15);
        int kb = (ks * 64 + ((lane >> 4) << 4)) ^ ((row & 7) << 4);
        bfr[j] = *(const bf16x8*)((const char*)Bs + row * 128 + kb);
      }
#pragma unroll
      for (int i = 0; i < 4; ++i)
#pragma unroll
        for (int j = 0; j < 4; ++j)
          acc[i][j] = __builtin_amdgcn_mfma_f32_16x16x32_bf16(af[i], bfr[j], acc[i][j], 0, 0, 0);
    }
  }

#pragma unroll
  for (int i = 0; i < 4; ++i) {
    int rowb = brow + wm * 64 + i * 16 + (lane >> 4) * 4;
#pragma unroll
    for (int j = 0; j < 4; ++j) {
      int col = bcol + wn * 64 + j * 16 + (lane & 15);
      float b = bias[col];
#pragma unroll
      for (int q = 0; q < 4; ++q) {
        int r = rowb + q;
        if (r < N) C[(size_t)r * DFEAT + col] = acc[i][j][q] + b;
      }
    }
  }
}

// ---------------- launch ----------------

extern "C" void kernel_launch(void* const* d_in, const int* in_sizes, int n_in,
                              void* d_out, int out_size, void* d_ws, size_t ws_size,
                              hipStream_t stream) {
  const float* x = (const float*)d_in[0];
  const int* ei = (const int*)d_in[1];
  const float* weight = (const float*)d_in[2];
  const float* bias = (const float*)d_in[3];
  float* out = (float*)d_out;

  int N = in_sizes[0] / DFEAT;
  int E = in_sizes[1] / 2;
  const int* ei0 = ei;
  const int* ei1 = ei + E;

  char* ws = (char*)d_ws;
  size_t off = 0;
  auto alloc = [&](size_t bytes) {
    void* p = ws + off;
    off = (off + bytes + 255) & ~(size_t)255;
    return p;
  };
  int* cnt = (int*)alloc((size_t)2 * N * sizeof(int));
  int* cursor = cnt + N;
  int* rowptr = (int*)alloc((size_t)(N + 1) * sizeof(int));
  float* dis = (float*)alloc((size_t)N * sizeof(float));
  int* cols = (int*)alloc((size_t)E * sizeof(int));
  int* incl = (int*)alloc((size_t)N * sizeof(int));
  int* bsum = (int*)alloc(256 * sizeof(int));
  int* boff = (int*)alloc(256 * sizeof(int));
  unsigned short* xbf = (unsigned short*)alloc((size_t)N * DFEAT * 2);
  unsigned short* B1 = (unsigned short*)alloc((size_t)N * DFEAT * 2);
  unsigned short* B2 = (unsigned short*)alloc((size_t)N * DFEAT * 2);
  unsigned short* B3 = (unsigned short*)alloc((size_t)N * DFEAT * 2);
  unsigned short* WT = (unsigned short*)alloc((size_t)4 * DFEAT * DFEAT * 2);

  hipMemsetAsync(cnt, 0, (size_t)2 * N * sizeof(int), stream);

  int eb = (E + 255) / 256;
  int nb = (N + 255) / 256;
  k_count<<<eb, 256, 0, stream>>>(ei0, E, cnt);
  k_scan1<<<nb, 256, 0, stream>>>(cnt, N, incl, bsum, dis);
  k_scan2<<<1, 256, 0, stream>>>(bsum, nb, boff);
  k_scan3<<<nb, 256, 0, stream>>>(cnt, incl, boff, N, E, rowptr);
  k_scatter<<<eb, 256, 0, stream>>>(ei0, ei1, E, rowptr, cursor, cols);

  int n4 = N * DFEAT / 4;
  k_f2bf<<<(n4 + 255) / 256, 256, 0, stream>>>(x, xbf, n4);
  k_wt<<<4 * DFEAT * DFEAT / 256, 256, 0, stream>>>(weight, WT);

  // T1 = L x ; T2 = 2 L T1 - x ; T3 = 2 L T2 - T1
  int sgrid = ((N + 15) / 16) * 8;
  k_spmm_ch<<<sgrid, 256, 0, stream>>>(xbf, xbf, B1, rowptr, cols, dis, 1.0f, 0.0f, N);
  k_spmm_ch<<<sgrid, 256, 0, stream>>>(B1, xbf, B2, rowptr, cols, dis, 2.0f, -1.0f, N);
  k_spmm_ch<<<sgrid, 256, 0, stream>>>(B2, B1, B3, rowptr, cols, dis, 2.0f, -1.0f, N);

  dim3 ggrid((N + 127) / 128, DFEAT / 128);
  k_gemm4<<<ggrid, 256, 0, stream>>>(xbf, B1, B2, B3, WT, bias, out, N);
}

// Round 5
// 360.824 us; speedup vs baseline: 1.7731x; 1.7731x over previous
//
#include <hip/hip_runtime.h>
#include <hip/hip_bf16.h>

#define DFEAT 256

typedef __attribute__((ext_vector_type(8))) short bf16x8;
typedef __attribute__((ext_vector_type(4))) float f32x4;

__device__ __forceinline__ float bf2f(unsigned short u) {
  return __builtin_bit_cast(float, ((unsigned)u) << 16);
}
__device__ __forceinline__ unsigned short f2bf(float f) {
  __hip_bfloat16 h = __float2bfloat16(f);  // RTNE
  return *reinterpret_cast<unsigned short*>(&h);
}
__device__ __forceinline__ void gload_lds16(const void* g, void* l) {
  __builtin_amdgcn_global_load_lds(
      (const __attribute__((address_space(1))) void*)g,
      (__attribute__((address_space(3))) void*)l, 16, 0, 0);
}

// ---------------- CSR construction ----------------

__global__ void k_count(const int* __restrict__ ei0, int E, int* __restrict__ cnt) {
  int i = blockIdx.x * blockDim.x + threadIdx.x;
  if (i < E) atomicAdd(&cnt[ei0[i]], 1);
}

__global__ __launch_bounds__(256) void k_scan1(const int* __restrict__ cnt, int N,
                                               int* __restrict__ incl,
                                               int* __restrict__ bsum,
                                               float* __restrict__ dis) {
  __shared__ int sh[256];
  int t = threadIdx.x;
  int i = blockIdx.x * 256 + t;
  int v = (i < N) ? cnt[i] : 0;
  sh[t] = v;
  __syncthreads();
  for (int o = 1; o < 256; o <<= 1) {
    int u = (t >= o) ? sh[t - o] : 0;
    __syncthreads();
    sh[t] += u;
    __syncthreads();
  }
  if (i < N) {
    incl[i] = sh[t];
    dis[i] = rsqrtf((float)(v + 1));
  }
  if (t == 255) bsum[blockIdx.x] = sh[255];
}

__global__ __launch_bounds__(256) void k_scan2(const int* __restrict__ bsum, int nb,
                                               int* __restrict__ boff) {
  __shared__ int sh[256];
  int t = threadIdx.x;
  int v = (t < nb) ? bsum[t] : 0;
  sh[t] = v;
  __syncthreads();
  for (int o = 1; o < 256; o <<= 1) {
    int u = (t >= o) ? sh[t - o] : 0;
    __syncthreads();
    sh[t] += u;
    __syncthreads();
  }
  if (t < nb) boff[t] = sh[t] - v;  // exclusive
}

__global__ __launch_bounds__(256) void k_scan3(const int* __restrict__ cnt,
                                               const int* __restrict__ incl,
                                               const int* __restrict__ boff, int N, int E,
                                               int* __restrict__ rowptr) {
  int i = blockIdx.x * 256 + threadIdx.x;
  if (i < N) rowptr[i] = boff[blockIdx.x] + incl[i] - cnt[i];
  if (i == 0) rowptr[N] = E;
}

__global__ void k_scatter(const int* __restrict__ ei0, const int* __restrict__ ei1, int E,
                          const int* __restrict__ rowptr, int* __restrict__ cursor,
                          int* __restrict__ cols) {
  int i = blockIdx.x * blockDim.x + threadIdx.x;
  if (i >= E) return;
  int r = ei0[i];
  int pos = rowptr[r] + atomicAdd(&cursor[r], 1);
  cols[pos] = ei1[i];
}

// ---------------- converts ----------------

__global__ void k_f2bf(const float* __restrict__ src, unsigned short* __restrict__ dst,
                       int n4) {
  int i = blockIdx.x * blockDim.x + threadIdx.x;
  if (i >= n4) return;
  float4 f = *(const float4*)(src + (size_t)i * 4);
  ushort4 u;
  u.x = f2bf(f.x); u.y = f2bf(f.y); u.z = f2bf(f.z); u.w = f2bf(f.w);
  *(ushort4*)(dst + (size_t)i * 4) = u;
}

// Combined weights for the pure-L chain:
//   out = x(W0-W2) + S1(W1-3W3) + S2(2W2) + S3(4W3) + b,  S_k = L^k x
// W[4][256][256] (g,k,n) f32 -> WT[4][256][256] (g,n,k) bf16 with combos.
__global__ __launch_bounds__(256) void k_wt(const float* __restrict__ W,
                                            unsigned short* __restrict__ WT) {
  int idx = blockIdx.x * 256 + threadIdx.x;  // (k,n) over 65536
  int n = idx & 255;
  int k = idx >> 8;
  float w0 = W[idx];
  float w1 = W[65536 + idx];
  float w2 = W[2 * 65536 + idx];
  float w3 = W[3 * 65536 + idx];
  int t = (n << 8) | k;  // transposed (n,k)
  WT[t]               = f2bf(w0 - w2);
  WT[65536 + t]       = f2bf(w1 - 3.0f * w3);
  WT[2 * 65536 + t]   = f2bf(2.0f * w2);
  WT[3 * 65536 + t]   = f2bf(4.0f * w3);
}

// ---------------- SpMM (bf16): y = L v  (pure Laplacian apply) ----------------
// 256 threads = 8 edge slots (half-wave each) x 32 lanes; lane covers 8 feats (16B).
// Laplacian value computed on the fly from dis (200 KB, cache-resident).

__global__ __launch_bounds__(256) void k_spmm_bf(
    const unsigned short* __restrict__ v, unsigned short* __restrict__ y,
    const int* __restrict__ rowptr, const int* __restrict__ cols,
    const float* __restrict__ dis) {
  __shared__ float red[3][32][9];  // +1 pad
  int r = blockIdx.x;
  int lane = threadIdx.x & 63;
  int w4 = threadIdx.x >> 6;
  int half = lane >> 5;
  int l32 = lane & 31;
  int slot = w4 * 2 + half;  // 0..7
  int fo = l32 * 8;
  float acc[8] = {};
  int e0 = rowptr[r], e1 = rowptr[r + 1];
  float dr = dis[r];

  int e = e0 + slot;
  for (; e + 8 < e1; e += 16) {
    int cA = cols[e], cB = cols[e + 8];
    float lA = -dr * dis[cA] + (cA == r ? 1.f : 0.f);
    float lB = -dr * dis[cB] + (cB == r ? 1.f : 0.f);
    uint4 uA = *(const uint4*)(v + (size_t)cA * DFEAT + fo);
    uint4 uB = *(const uint4*)(v + (size_t)cB * DFEAT + fo);
    const unsigned int* wa = &uA.x;
    const unsigned int* wb = &uB.x;
#pragma unroll
    for (int j = 0; j < 4; ++j) {
      acc[2 * j]     += lA * bf2f(wa[j] & 0xffff) + lB * bf2f(wb[j] & 0xffff);
      acc[2 * j + 1] += lA * bf2f(wa[j] >> 16)    + lB * bf2f(wb[j] >> 16);
    }
  }
  if (e < e1) {
    int c = cols[e];
    float lv = -dr * dis[c] + (c == r ? 1.f : 0.f);
    uint4 u = *(const uint4*)(v + (size_t)c * DFEAT + fo);
    const unsigned int* wu = &u.x;
#pragma unroll
    for (int j = 0; j < 4; ++j) {
      acc[2 * j]     += lv * bf2f(wu[j] & 0xffff);
      acc[2 * j + 1] += lv * bf2f(wu[j] >> 16);
    }
  }

#pragma unroll
  for (int j = 0; j < 8; ++j) acc[j] += __shfl_xor(acc[j], 32);

  if (w4 && !half) {
#pragma unroll
    for (int j = 0; j < 8; ++j) red[w4 - 1][l32][j] = acc[j];
  }
  __syncthreads();
  if (w4 == 0 && !half) {
    float sc = 1.0f - dr * dr;  // appended self-loop value
    uint4 uv = *(const uint4*)(v + (size_t)r * DFEAT + fo);
    const unsigned int* vu = &uv.x;
    ushort4 o[2];
    unsigned short* op = &o[0].x;
#pragma unroll
    for (int j = 0; j < 8; ++j) {
      float a = acc[j] + red[0][l32][j] + red[1][l32][j] + red[2][l32][j];
      float selfv = (j & 1) ? bf2f(vu[j >> 1] >> 16) : bf2f(vu[j >> 1] & 0xffff);
      op[j] = f2bf(a + sc * selfv);
    }
    *(uint4*)(y + (size_t)r * DFEAT + fo) = *(const uint4*)&o[0];
  }
}

// ---------------- fused MFMA GEMM: out = sum_g Ag @ Wg' + bias ----------------
// 128x128 tile, 4 waves, double-buffered LDS, 2-phase overlap (stage next while
// computing current; one __syncthreads (vmcnt0+barrier) per K-step).

__global__ __launch_bounds__(256) void k_gemm4(
    const unsigned short* __restrict__ A0, const unsigned short* __restrict__ A1,
    const unsigned short* __restrict__ A2, const unsigned short* __restrict__ A3,
    const unsigned short* __restrict__ WT,  // [4][256][256] (g,n,k) combined
    const float* __restrict__ bias, float* __restrict__ C, int N) {
  __shared__ __align__(16) unsigned short As[2][128 * 64];
  __shared__ __align__(16) unsigned short Bs[2][128 * 64];
  int tid = threadIdx.x;
  int lane = tid & 63;
  int w = tid >> 6;
  int wm = w >> 1, wn = w & 1;
  int brow = blockIdx.x * 128;
  int bcol = blockIdx.y * 128;

  f32x4 acc[4][4] = {};

  int srow = w * 32 + (lane >> 3);
  int skb = ((lane & 7) ^ (lane >> 3)) << 4;

  auto stage = [&](int buf, int it) {
    int g = it >> 2;
    int k0 = (it & 3) * 64;
    const unsigned short* Asrc = g == 0 ? A0 : g == 1 ? A1 : g == 2 ? A2 : A3;
    const unsigned short* Bsrc = WT + (g << 16);
#pragma unroll
    for (int c = 0; c < 4; ++c) {
      int r = srow + c * 8;
      int grow = brow + r;
      if (grow >= N) grow = N - 1;
      gload_lds16(Asrc + (size_t)grow * DFEAT + k0 + (skb >> 1),
                  (char*)As[buf] + (w * 32 + c * 8) * 128);
      gload_lds16(Bsrc + (size_t)(bcol + r) * DFEAT + k0 + (skb >> 1),
                  (char*)Bs[buf] + (w * 32 + c * 8) * 128);
    }
  };

  stage(0, 0);
  __syncthreads();  // vmcnt(0) + barrier: tile 0 ready

  for (int it = 0; it < 16; ++it) {
    int cur = it & 1;
    if (it < 15) stage(cur ^ 1, it + 1);  // issue next tile, stays in flight
#pragma unroll
    for (int ks = 0; ks < 2; ++ks) {
      bf16x8 af[4], bfr[4];
#pragma unroll
      for (int i = 0; i < 4; ++i) {
        int row = wm * 64 + i * 16 + (lane & 15);
        int kb = (ks * 64 + ((lane >> 4) << 4)) ^ ((row & 7) << 4);
        af[i] = *(const bf16x8*)((const char*)As[cur] + row * 128 + kb);
      }
#pragma unroll
      for (int j = 0; j < 4; ++j) {
        int row = wn * 64 + j * 16 + (lane & 15);
        int kb = (ks * 64 + ((lane >> 4) << 4)) ^ ((row & 7) << 4);
        bfr[j] = *(const bf16x8*)((const char*)Bs[cur] + row * 128 + kb);
      }
#pragma unroll
      for (int i = 0; i < 4; ++i)
#pragma unroll
        for (int j = 0; j < 4; ++j)
          acc[i][j] = __builtin_amdgcn_mfma_f32_16x16x32_bf16(af[i], bfr[j], acc[i][j], 0, 0, 0);
    }
    if (it < 15) __syncthreads();  // drain next-tile loads + guard buffer reuse
  }

#pragma unroll
  for (int i = 0; i < 4; ++i) {
    int rowb = brow + wm * 64 + i * 16 + (lane >> 4) * 4;
#pragma unroll
    for (int j = 0; j < 4; ++j) {
      int col = bcol + wn * 64 + j * 16 + (lane & 15);
      float b = bias[col];
#pragma unroll
      for (int q = 0; q < 4; ++q) {
        int r = rowb + q;
        if (r < N) C[(size_t)r * DFEAT + col] = acc[i][j][q] + b;
      }
    }
  }
}

// ---------------- launch ----------------

extern "C" void kernel_launch(void* const* d_in, const int* in_sizes, int n_in,
                              void* d_out, int out_size, void* d_ws, size_t ws_size,
                              hipStream_t stream) {
  const float* x = (const float*)d_in[0];
  const int* ei = (const int*)d_in[1];
  const float* weight = (const float*)d_in[2];
  const float* bias = (const float*)d_in[3];
  float* out = (float*)d_out;

  int N = in_sizes[0] / DFEAT;
  int E = in_sizes[1] / 2;
  const int* ei0 = ei;
  const int* ei1 = ei + E;

  char* ws = (char*)d_ws;
  size_t off = 0;
  auto alloc = [&](size_t bytes) {
    void* p = ws + off;
    off = (off + bytes + 255) & ~(size_t)255;
    return p;
  };
  int* cnt = (int*)alloc((size_t)2 * N * sizeof(int));
  int* cursor = cnt + N;
  int* rowptr = (int*)alloc((size_t)(N + 1) * sizeof(int));
  float* dis = (float*)alloc((size_t)N * sizeof(float));
  int* cols = (int*)alloc((size_t)E * sizeof(int));
  int* incl = (int*)alloc((size_t)N * sizeof(int));
  int* bsum = (int*)alloc(256 * sizeof(int));
  int* boff = (int*)alloc(256 * sizeof(int));
  unsigned short* xbf = (unsigned short*)alloc((size_t)N * DFEAT * 2);
  unsigned short* S1 = (unsigned short*)alloc((size_t)N * DFEAT * 2);
  unsigned short* S2 = (unsigned short*)alloc((size_t)N * DFEAT * 2);
  unsigned short* S3 = (unsigned short*)alloc((size_t)N * DFEAT * 2);
  unsigned short* WT = (unsigned short*)alloc((size_t)4 * DFEAT * DFEAT * 2);

  hipMemsetAsync(cnt, 0, (size_t)2 * N * sizeof(int), stream);

  int eb = (E + 255) / 256;
  int nb = (N + 255) / 256;
  k_count<<<eb, 256, 0, stream>>>(ei0, E, cnt);
  k_scan1<<<nb, 256, 0, stream>>>(cnt, N, incl, bsum, dis);
  k_scan2<<<1, 256, 0, stream>>>(bsum, nb, boff);
  k_scan3<<<nb, 256, 0, stream>>>(cnt, incl, boff, N, E, rowptr);
  k_scatter<<<eb, 256, 0, stream>>>(ei0, ei1, E, rowptr, cursor, cols);

  int n4 = N * DFEAT / 4;
  k_f2bf<<<(n4 + 255) / 256, 256, 0, stream>>>(x, xbf, n4);
  k_wt<<<DFEAT * DFEAT / 256, 256, 0, stream>>>(weight, WT);

  // Pure chain: S1 = L x ; S2 = L S1 ; S3 = L S2
  k_spmm_bf<<<N, 256, 0, stream>>>(xbf, S1, rowptr, cols, dis);
  k_spmm_bf<<<N, 256, 0, stream>>>(S1, S2, rowptr, cols, dis);
  k_spmm_bf<<<N, 256, 0, stream>>>(S2, S3, rowptr, cols, dis);

  dim3 ggrid((N + 127) / 128, DFEAT / 128);
  k_gemm4<<<ggrid, 256, 0, stream>>>(xbf, S1, S2, S3, WT, bias, out, N);
}